// Round 4
// baseline (1516.442 us; speedup 1.0000x reference)
//
#include <hip/hip_runtime.h>
#include <hip/hip_bf16.h>

#define NN 50000
#define EE 800000

// ---------- helpers ----------
__device__ __forceinline__ unsigned encf(float f) {
    unsigned u = __float_as_uint(f);
    return (u & 0x80000000u) ? ~u : (u | 0x80000000u);
}
__device__ __forceinline__ float decf(unsigned u) {
    return (u & 0x80000000u) ? __uint_as_float(u & 0x7fffffffu)
                             : __uint_as_float(~u);
}
// packed bf16 (2 per u32) -> floats (exact)
__device__ __forceinline__ float bfu_lo(unsigned w) { return __uint_as_float(w << 16); }
__device__ __forceinline__ float bfu_hi(unsigned w) { return __uint_as_float(w & 0xffff0000u); }

// ---------- zero words ----------
__global__ __launch_bounds__(256) void zero_kernel(unsigned* __restrict__ p, int n) {
    int i = blockIdx.x * 256 + threadIdx.x;
    if (i < n) p[i] = 0u;
}

// ---------- GEMM: out[n,128] = x[n,128] @ w[128,128] + b ----------
// Block: 16 rows x 64 cols; blockIdx.y = column half. LDS 40.3 KB.
// OUT_BF16: write bf16 (for Q/K/V) else f32.
template <bool OUT_BF16>
__global__ __launch_bounds__(256) void proj_kernel(
    const float* __restrict__ x, const float* __restrict__ w,
    const float* __restrict__ b, void* __restrict__ outv, int n) {
    __shared__ float wl[128 * 64];
    __shared__ float xl[16 * 128];
    __shared__ float bl[64];
    int tid = threadIdx.x;
    int col0 = blockIdx.y * 64;
    for (int i = tid; i < 128 * 64; i += 256)
        wl[i] = w[(i >> 6) * 128 + col0 + (i & 63)];
    if (tid < 64) bl[tid] = b[col0 + tid];
    __syncthreads();

    int sub = tid >> 6;     // 0..3
    int col = tid & 63;
    int ngrp = n >> 4;
    for (int g = blockIdx.x; g < ngrp; g += gridDim.x) {
        int r0 = g << 4;
        __syncthreads();
        const float4* xs = (const float4*)(x + (size_t)r0 * 128);
        ((float4*)xl)[tid] = xs[tid];
        ((float4*)xl)[tid + 256] = xs[tid + 256];
        __syncthreads();
        float a0 = bl[col], a1 = a0, a2 = a0, a3 = a0;
#pragma unroll
        for (int k = 0; k < 128; ++k) {
            float wv = wl[k * 64 + col];
            a0 = fmaf(xl[(sub + 0) * 128 + k], wv, a0);
            a1 = fmaf(xl[(sub + 4) * 128 + k], wv, a1);
            a2 = fmaf(xl[(sub + 8) * 128 + k], wv, a2);
            a3 = fmaf(xl[(sub + 12) * 128 + k], wv, a3);
        }
        size_t base = (size_t)r0 * 128 + col0 + col;
        if (OUT_BF16) {
            __hip_bfloat16* o = (__hip_bfloat16*)outv;
            o[base + (size_t)(sub + 0) * 128] = __float2bfloat16(a0);
            o[base + (size_t)(sub + 4) * 128] = __float2bfloat16(a1);
            o[base + (size_t)(sub + 8) * 128] = __float2bfloat16(a2);
            o[base + (size_t)(sub + 12) * 128] = __float2bfloat16(a3);
        } else {
            float* o = (float*)outv;
            o[base + (size_t)(sub + 0) * 128] = a0;
            o[base + (size_t)(sub + 4) * 128] = a1;
            o[base + (size_t)(sub + 8) * 128] = a2;
            o[base + (size_t)(sub + 12) * 128] = a3;
        }
    }
}

// ---------- in-place GEMM: xo[n,128] = xo[n,128] @ w + b ----------
// Block owns each 16-row group; stages rows in LDS BEFORE overwriting.
__global__ __launch_bounds__(256) void proj_inplace_kernel(
    float* __restrict__ xo, const float* __restrict__ w,
    const float* __restrict__ b, int n) {
    __shared__ float wl[128 * 64];
    __shared__ float xl[16 * 128];
    __shared__ float bl[128];
    int tid = threadIdx.x;
    if (tid < 128) bl[tid] = b[tid];
    int sub = tid >> 6;
    int col = tid & 63;
    int ngrp = n >> 4;
    for (int g = blockIdx.x; g < ngrp; g += gridDim.x) {
        int r0 = g << 4;
        __syncthreads();
        const float4* xs = (const float4*)(xo + (size_t)r0 * 128);
        ((float4*)xl)[tid] = xs[tid];
        ((float4*)xl)[tid + 256] = xs[tid + 256];
#pragma unroll 1
        for (int half = 0; half < 2; ++half) {
            int col0 = half * 64;
            for (int i = tid; i < 128 * 64; i += 256)
                wl[i] = w[(i >> 6) * 128 + col0 + (i & 63)];
            __syncthreads();
            float a0 = bl[col0 + col], a1 = a0, a2 = a0, a3 = a0;
#pragma unroll
            for (int k = 0; k < 128; ++k) {
                float wv = wl[k * 64 + col];
                a0 = fmaf(xl[(sub + 0) * 128 + k], wv, a0);
                a1 = fmaf(xl[(sub + 4) * 128 + k], wv, a1);
                a2 = fmaf(xl[(sub + 8) * 128 + k], wv, a2);
                a3 = fmaf(xl[(sub + 12) * 128 + k], wv, a3);
            }
            size_t base = (size_t)r0 * 128 + col0 + col;
            xo[base + (size_t)(sub + 0) * 128] = a0;
            xo[base + (size_t)(sub + 4) * 128] = a1;
            xo[base + (size_t)(sub + 8) * 128] = a2;
            xo[base + (size_t)(sub + 12) * 128] = a3;
            __syncthreads();
        }
    }
}

// ---------- edge logits (bf16 Q/K) + atomicMax ----------
template <int H, int C>
__global__ __launch_bounds__(256) void logits_kernel(
    const __hip_bfloat16* __restrict__ Q, const __hip_bfloat16* __restrict__ K,
    const int* __restrict__ src, const int* __restrict__ dst,
    float* __restrict__ LG, unsigned* __restrict__ MX, float scale) {
    int e = blockIdx.x * 256 + threadIdx.x;
    if (e >= EE) return;
    int s = src[e], d = dst[e];
    const uint4* q = (const uint4*)(Q + (size_t)d * 128);   // 16B = 8 bf16
    const uint4* k = (const uint4*)(K + (size_t)s * 128);
#pragma unroll
    for (int h = 0; h < H; ++h) {
        float acc = 0.f;
#pragma unroll
        for (int i = 0; i < C / 8; ++i) {
            uint4 a = q[h * (C / 8) + i];
            uint4 bb = k[h * (C / 8) + i];
            acc += bfu_lo(a.x) * bfu_lo(bb.x) + bfu_hi(a.x) * bfu_hi(bb.x);
            acc += bfu_lo(a.y) * bfu_lo(bb.y) + bfu_hi(a.y) * bfu_hi(bb.y);
            acc += bfu_lo(a.z) * bfu_lo(bb.z) + bfu_hi(a.z) * bfu_hi(bb.z);
            acc += bfu_lo(a.w) * bfu_lo(bb.w) + bfu_hi(a.w) * bfu_hi(bb.w);
        }
        float lg = acc * scale;
        LG[(size_t)e * H + h] = lg;
        atomicMax(&MX[d * H + h], encf(lg));
    }
}

// ---------- exp(logit - max) + atomicAdd denominator ----------
template <int H>
__global__ __launch_bounds__(256) void expsum_kernel(
    float* __restrict__ LG, const unsigned* __restrict__ MX,
    const int* __restrict__ dst, float* __restrict__ SM) {
    int i = blockIdx.x * 256 + threadIdx.x;
    if (i >= EE * H) return;
    int e = (H == 1) ? i : (i >> 2);
    int h = (H == 1) ? 0 : (i & 3);
    int d = dst[e];
    float m = decf(MX[d * H + h]);
    float ev = expf(LG[i] - m);
    LG[i] = ev;
    atomicAdd(&SM[d * H + h], ev);
}

// ---------- scatter alpha * V[src] into O[dst] (V in bf16) ----------
template <int H, int C>
__global__ __launch_bounds__(256) void scatter_kernel(
    const float* __restrict__ LG, const float* __restrict__ SM,
    const __hip_bfloat16* __restrict__ V, const int* __restrict__ src,
    const int* __restrict__ dst, float* __restrict__ O) {
    long long i = (long long)blockIdx.x * 256 + threadIdx.x;
    if (i >= (long long)EE * 128) return;
    int e = (int)(i >> 7);
    int c = (int)(i & 127);
    int h = (C == 128) ? 0 : (c >> 5);
    int s = src[e], d = dst[e];
    float alpha = LG[(size_t)e * H + h] / (SM[d * H + h] + 1e-16f);
    unsigned short vb = ((const unsigned short*)V)[(size_t)s * 128 + c];
    float v = __uint_as_float((unsigned)vb << 16);
    atomicAdd(&O[(size_t)d * 128 + c], alpha * v);
}

// ---------- relu (in-place) ----------
__global__ __launch_bounds__(256) void relu_kernel(float* __restrict__ a, int n) {
    int i = blockIdx.x * 256 + threadIdx.x;
    if (i < n) a[i] = fmaxf(a[i], 0.f);
}

extern "C" void kernel_launch(void* const* d_in, const int* in_sizes, int n_in,
                              void* d_out, int out_size, void* d_ws, size_t ws_size,
                              hipStream_t stream) {
    const float* x  = (const float*)d_in[0];
    const int* ei   = (const int*)d_in[1];
    const int* src  = ei;
    const int* dst  = ei + EE;
    const float* w1q = (const float*)d_in[2];  const float* b1q = (const float*)d_in[3];
    const float* w1k = (const float*)d_in[4];  const float* b1k = (const float*)d_in[5];
    const float* w1v = (const float*)d_in[6];  const float* b1v = (const float*)d_in[7];
    const float* w1s = (const float*)d_in[8];  const float* b1s = (const float*)d_in[9];
    const float* w2q = (const float*)d_in[10]; const float* b2q = (const float*)d_in[11];
    const float* w2k = (const float*)d_in[12]; const float* b2k = (const float*)d_in[13];
    const float* w2v = (const float*)d_in[14]; const float* b2v = (const float*)d_in[15];
    const float* w2s = (const float*)d_in[16]; const float* b2s = (const float*)d_in[17];
    float* out = (float*)d_out;   // layer-1 accumulator, h, and final output

    const size_t NF = (size_t)NN * 128;
    // ws layout (52.8 MB total):
    unsigned* MX = (unsigned*)d_ws;                         // N*4 u32
    float* SM = (float*)d_ws + (size_t)NN * 4;              // N*4 f32
    float* LG = (float*)d_ws + (size_t)NN * 8;              // E*4 f32
    __hip_bfloat16* Qb = (__hip_bfloat16*)(LG + (size_t)EE * 4);  // N*128 bf16
    __hip_bfloat16* Kb = Qb + NF;
    __hip_bfloat16* Vb = Kb + NF;

    const dim3 PG(512, 2);
    const int EB = (EE + 255) / 256;
    const int ZB = (NN * 8 + 255) / 256;

    // ===== layer 1 (heads=4, ch=32) =====
    zero_kernel<<<ZB, 256, 0, stream>>>(MX, NN * 8);   // MX+SM contiguous
    proj_kernel<true><<<PG, 256, 0, stream>>>(x, w1q, b1q, Qb, NN);
    proj_kernel<true><<<PG, 256, 0, stream>>>(x, w1k, b1k, Kb, NN);
    proj_kernel<true><<<PG, 256, 0, stream>>>(x, w1v, b1v, Vb, NN);
    proj_kernel<false><<<PG, 256, 0, stream>>>(x, w1s, b1s, out, NN);  // skip
    logits_kernel<4, 32><<<EB, 256, 0, stream>>>(Qb, Kb, src, dst, LG, MX,
                                                 0.17677669529663687f);
    expsum_kernel<4><<<(EE * 4 + 255) / 256, 256, 0, stream>>>(LG, MX, dst, SM);
    {
        long long tot = (long long)EE * 128;
        scatter_kernel<4, 32><<<(int)((tot + 255) / 256), 256, 0, stream>>>(
            LG, SM, Vb, src, dst, out);
    }
    relu_kernel<<<(int)((NF + 255) / 256), 256, 0, stream>>>(out, (int)NF);

    // ===== layer 2 (heads=1, ch=128); h lives in `out` =====
    zero_kernel<<<ZB, 256, 0, stream>>>(MX, NN * 8);
    proj_kernel<true><<<PG, 256, 0, stream>>>(out, w2q, b2q, Qb, NN);
    proj_kernel<true><<<PG, 256, 0, stream>>>(out, w2k, b2k, Kb, NN);
    proj_kernel<true><<<PG, 256, 0, stream>>>(out, w2v, b2v, Vb, NN);
    logits_kernel<1, 128><<<EB, 256, 0, stream>>>(Qb, Kb, src, dst, LG, MX,
                                                  0.08838834764831845f);
    expsum_kernel<1><<<(EE + 255) / 256, 256, 0, stream>>>(LG, MX, dst, SM);
    // skip projection: last consumer of h, then safe to overwrite in place
    proj_inplace_kernel<<<512, 256, 0, stream>>>(out, w2s, b2s, NN);
    {
        long long tot = (long long)EE * 128;
        scatter_kernel<1, 128><<<(int)((tot + 255) / 256), 256, 0, stream>>>(
            LG, SM, Vb, src, dst, out);
    }
}

// Round 5
// 972.622 us; speedup vs baseline: 1.5591x; 1.5591x over previous
//
#include <hip/hip_runtime.h>
#include <hip/hip_bf16.h>

#define NN 50000
#define EE 800000

// ---------- helpers ----------
__device__ __forceinline__ float bfu_lo(unsigned w) { return __uint_as_float(w << 16); }
__device__ __forceinline__ float bfu_hi(unsigned w) { return __uint_as_float(w & 0xffff0000u); }

// ---------- zero words ----------
__global__ __launch_bounds__(256) void zero_kernel(unsigned* __restrict__ p, int n) {
    int i = blockIdx.x * 256 + threadIdx.x;
    if (i < n) p[i] = 0u;
}

// ---------- CSR build: histogram ----------
__global__ __launch_bounds__(256) void hist_kernel(
    const int* __restrict__ dst, unsigned* __restrict__ deg) {
    int e = blockIdx.x * 256 + threadIdx.x;
    if (e < EE) atomicAdd(&deg[dst[e]], 1u);
}

// ---------- CSR build: exclusive scan (single block, 1024 thr) ----------
__global__ __launch_bounds__(1024) void scan_kernel(
    const unsigned* __restrict__ deg, unsigned* __restrict__ rp,
    unsigned* __restrict__ cursor) {
    __shared__ unsigned s[1024];
    __shared__ unsigned carry;
    int tid = threadIdx.x;
    if (tid == 0) carry = 0;
    __syncthreads();
    for (int base = 0; base < NN; base += 1024) {
        int i = base + tid;
        unsigned v = (i < NN) ? deg[i] : 0u;
        s[tid] = v;
        __syncthreads();
        for (int o = 1; o < 1024; o <<= 1) {
            unsigned t2 = (tid >= o) ? s[tid - o] : 0u;
            __syncthreads();
            s[tid] += t2;
            __syncthreads();
        }
        unsigned c = carry;
        if (i < NN) { unsigned excl = s[tid] - v + c; rp[i] = excl; cursor[i] = excl; }
        __syncthreads();
        if (tid == 1023) carry = c + s[1023];
        __syncthreads();
    }
    if (tid == 0) rp[NN] = carry;   // == EE
}

// ---------- CSR build: fill ----------
__global__ __launch_bounds__(256) void fill_kernel(
    const int* __restrict__ src, const int* __restrict__ dst,
    unsigned* __restrict__ cursor, int* __restrict__ es, int* __restrict__ eidx) {
    int e = blockIdx.x * 256 + threadIdx.x;
    if (e >= EE) return;
    unsigned pos = atomicAdd(&cursor[dst[e]], 1u);
    es[pos] = src[e];
    eidx[pos] = e;
}

// ---------- GEMM: out[n,128] = x[n,128] @ w[128,128] + b ----------
template <bool OUT_BF16>
__global__ __launch_bounds__(256) void proj_kernel(
    const float* __restrict__ x, const float* __restrict__ w,
    const float* __restrict__ b, void* __restrict__ outv, int n) {
    __shared__ float wl[128 * 64];
    __shared__ float xl[16 * 128];
    __shared__ float bl[64];
    int tid = threadIdx.x;
    int col0 = blockIdx.y * 64;
    for (int i = tid; i < 128 * 64; i += 256)
        wl[i] = w[(i >> 6) * 128 + col0 + (i & 63)];
    if (tid < 64) bl[tid] = b[col0 + tid];
    __syncthreads();

    int sub = tid >> 6;
    int col = tid & 63;
    int ngrp = n >> 4;
    for (int g = blockIdx.x; g < ngrp; g += gridDim.x) {
        int r0 = g << 4;
        __syncthreads();
        const float4* xs = (const float4*)(x + (size_t)r0 * 128);
        ((float4*)xl)[tid] = xs[tid];
        ((float4*)xl)[tid + 256] = xs[tid + 256];
        __syncthreads();
        float a0 = bl[col], a1 = a0, a2 = a0, a3 = a0;
#pragma unroll
        for (int k = 0; k < 128; ++k) {
            float wv = wl[k * 64 + col];
            a0 = fmaf(xl[(sub + 0) * 128 + k], wv, a0);
            a1 = fmaf(xl[(sub + 4) * 128 + k], wv, a1);
            a2 = fmaf(xl[(sub + 8) * 128 + k], wv, a2);
            a3 = fmaf(xl[(sub + 12) * 128 + k], wv, a3);
        }
        size_t base = (size_t)r0 * 128 + col0 + col;
        if (OUT_BF16) {
            __hip_bfloat16* o = (__hip_bfloat16*)outv;
            o[base + (size_t)(sub + 0) * 128] = __float2bfloat16(a0);
            o[base + (size_t)(sub + 4) * 128] = __float2bfloat16(a1);
            o[base + (size_t)(sub + 8) * 128] = __float2bfloat16(a2);
            o[base + (size_t)(sub + 12) * 128] = __float2bfloat16(a3);
        } else {
            float* o = (float*)outv;
            o[base + (size_t)(sub + 0) * 128] = a0;
            o[base + (size_t)(sub + 4) * 128] = a1;
            o[base + (size_t)(sub + 8) * 128] = a2;
            o[base + (size_t)(sub + 12) * 128] = a3;
        }
    }
}

// ---------- in-place GEMM: xo = xo @ w + b ----------
__global__ __launch_bounds__(256) void proj_inplace_kernel(
    float* __restrict__ xo, const float* __restrict__ w,
    const float* __restrict__ b, int n) {
    __shared__ float wl[128 * 64];
    __shared__ float xl[16 * 128];
    __shared__ float bl[128];
    int tid = threadIdx.x;
    if (tid < 128) bl[tid] = b[tid];
    int sub = tid >> 6;
    int col = tid & 63;
    int ngrp = n >> 4;
    for (int g = blockIdx.x; g < ngrp; g += gridDim.x) {
        int r0 = g << 4;
        __syncthreads();
        const float4* xs = (const float4*)(xo + (size_t)r0 * 128);
        ((float4*)xl)[tid] = xs[tid];
        ((float4*)xl)[tid + 256] = xs[tid + 256];
#pragma unroll 1
        for (int half = 0; half < 2; ++half) {
            int col0 = half * 64;
            for (int i = tid; i < 128 * 64; i += 256)
                wl[i] = w[(i >> 6) * 128 + col0 + (i & 63)];
            __syncthreads();
            float a0 = bl[col0 + col], a1 = a0, a2 = a0, a3 = a0;
#pragma unroll
            for (int k = 0; k < 128; ++k) {
                float wv = wl[k * 64 + col];
                a0 = fmaf(xl[(sub + 0) * 128 + k], wv, a0);
                a1 = fmaf(xl[(sub + 4) * 128 + k], wv, a1);
                a2 = fmaf(xl[(sub + 8) * 128 + k], wv, a2);
                a3 = fmaf(xl[(sub + 12) * 128 + k], wv, a3);
            }
            size_t base = (size_t)r0 * 128 + col0 + col;
            xo[base + (size_t)(sub + 0) * 128] = a0;
            xo[base + (size_t)(sub + 4) * 128] = a1;
            xo[base + (size_t)(sub + 8) * 128] = a2;
            xo[base + (size_t)(sub + 12) * 128] = a3;
            __syncthreads();
        }
    }
}

// ---------- edge logits (bf16 Q/K), no atomics ----------
template <int H, int C>
__global__ __launch_bounds__(256) void logits_kernel(
    const __hip_bfloat16* __restrict__ Q, const __hip_bfloat16* __restrict__ K,
    const int* __restrict__ src, const int* __restrict__ dst,
    float* __restrict__ LG, float scale) {
    int e = blockIdx.x * 256 + threadIdx.x;
    if (e >= EE) return;
    int s = src[e], d = dst[e];
    const uint4* q = (const uint4*)(Q + (size_t)d * 128);
    const uint4* k = (const uint4*)(K + (size_t)s * 128);
#pragma unroll
    for (int h = 0; h < H; ++h) {
        float acc = 0.f;
#pragma unroll
        for (int i = 0; i < C / 8; ++i) {
            uint4 a = q[h * (C / 8) + i];
            uint4 bb = k[h * (C / 8) + i];
            acc += bfu_lo(a.x) * bfu_lo(bb.x) + bfu_hi(a.x) * bfu_hi(bb.x);
            acc += bfu_lo(a.y) * bfu_lo(bb.y) + bfu_hi(a.y) * bfu_hi(bb.y);
            acc += bfu_lo(a.z) * bfu_lo(bb.z) + bfu_hi(a.z) * bfu_hi(bb.z);
            acc += bfu_lo(a.w) * bfu_lo(bb.w) + bfu_hi(a.w) * bfu_hi(bb.w);
        }
        LG[(size_t)e * H + h] = acc * scale;
    }
}

// ---------- per-dst gather with online softmax ----------
// one 128-thread block per dst node; chunked over its CSR edge range.
template <int H, bool RELU>
__global__ __launch_bounds__(128) void gather_kernel(
    const float* __restrict__ LG, const __hip_bfloat16* __restrict__ V,
    const unsigned* __restrict__ rp, const int* __restrict__ es,
    const int* __restrict__ eidx, float* __restrict__ O) {
    __shared__ float Pl[128 * H];
    __shared__ int esl[128];
    __shared__ float red[128];
    int d = blockIdx.x;
    int tid = threadIdx.x;
    int beg = (int)rp[d], end = (int)rp[d + 1];
    const int h = (H == 4) ? (tid >> 5) : 0;
    const int l = (H == 4) ? (tid & 31) : tid;
    const int L = (H == 4) ? 32 : 128;
    float m = -3.4e38f, ssum = 0.f, acc = 0.f;
    for (int cs = beg; cs < end; cs += 128) {
        int len = min(128, end - cs);
        __syncthreads();   // Pl/esl safe to overwrite
        if (tid < len) {
            int e = eidx[cs + tid];
            esl[tid] = es[cs + tid];
            if (H == 4) {
                float4 lg = ((const float4*)LG)[e];
                Pl[tid * 4 + 0] = lg.x; Pl[tid * 4 + 1] = lg.y;
                Pl[tid * 4 + 2] = lg.z; Pl[tid * 4 + 3] = lg.w;
            } else {
                Pl[tid] = LG[e];
            }
        }
        __syncthreads();
        // chunk max for own head
        float pm = -3.4e38f;
        for (int j = l; j < len; j += L) pm = fmaxf(pm, Pl[j * H + h]);
        red[tid] = pm;
        __syncthreads();
#pragma unroll
        for (int o = L >> 1; o > 0; o >>= 1) {
            float v2 = fmaxf(red[tid], red[tid ^ o]);
            __syncthreads();
            red[tid] = v2;
            __syncthreads();
        }
        float cm = red[tid];
        float nm = fmaxf(m, cm);
        float sc = __expf(m - nm);     // exp(-inf)=0 on first chunk
        // exp in place + partial sum
        float ps = 0.f;
        for (int j = l; j < len; j += L) {
            float v2 = __expf(Pl[j * H + h] - nm);
            Pl[j * H + h] = v2;
            ps += v2;
        }
        __syncthreads();
        red[tid] = ps;
        __syncthreads();
#pragma unroll
        for (int o = L >> 1; o > 0; o >>= 1) {
            float v2 = red[tid] + red[tid ^ o];
            __syncthreads();
            red[tid] = v2;
            __syncthreads();
        }
        ssum = ssum * sc + red[tid];
        acc *= sc;
        m = nm;
        // accumulate P * V[src]
        for (int j = 0; j < len; ++j) {
            float w = Pl[j * H + h];
            unsigned short vb = ((const unsigned short*)V)[(size_t)esl[j] * 128 + tid];
            acc = fmaf(w, __uint_as_float((unsigned)vb << 16), acc);
        }
    }
    size_t oi = (size_t)d * 128 + tid;
    float val = O[oi] + acc / (ssum + 1e-16f);
    if (RELU) val = fmaxf(val, 0.f);
    O[oi] = val;
}

extern "C" void kernel_launch(void* const* d_in, const int* in_sizes, int n_in,
                              void* d_out, int out_size, void* d_ws, size_t ws_size,
                              hipStream_t stream) {
    const float* x  = (const float*)d_in[0];
    const int* ei   = (const int*)d_in[1];
    const int* src  = ei;
    const int* dst  = ei + EE;
    const float* w1q = (const float*)d_in[2];  const float* b1q = (const float*)d_in[3];
    const float* w1k = (const float*)d_in[4];  const float* b1k = (const float*)d_in[5];
    const float* w1v = (const float*)d_in[6];  const float* b1v = (const float*)d_in[7];
    const float* w1s = (const float*)d_in[8];  const float* b1s = (const float*)d_in[9];
    const float* w2q = (const float*)d_in[10]; const float* b2q = (const float*)d_in[11];
    const float* w2k = (const float*)d_in[12]; const float* b2k = (const float*)d_in[13];
    const float* w2v = (const float*)d_in[14]; const float* b2v = (const float*)d_in[15];
    const float* w2s = (const float*)d_in[16]; const float* b2s = (const float*)d_in[17];
    float* out = (float*)d_out;   // layer-1 accumulator, h, final output

    const size_t NF = (size_t)NN * 128;
    // ws layout (~58.2 MB): LG first (16B-aligned), then bf16 QKV, then CSR ints
    float* LG = (float*)d_ws;                                     // E*4 f32
    __hip_bfloat16* Qb = (__hip_bfloat16*)(LG + (size_t)EE * 4);  // N*128 bf16
    __hip_bfloat16* Kb = Qb + NF;
    __hip_bfloat16* Vb = Kb + NF;
    unsigned* deg = (unsigned*)(Vb + NF);                         // N
    unsigned* cursor = deg + NN;                                  // N
    unsigned* rp = cursor + NN;                                   // N+1
    int* es = (int*)(rp + NN + 1);                                // E
    int* eidx = es + EE;                                          // E

    const dim3 PG(512, 2);
    const int EB = (EE + 255) / 256;

    // ===== CSR build (shared by both layers) =====
    zero_kernel<<<(NN + 255) / 256, 256, 0, stream>>>(deg, NN);
    hist_kernel<<<EB, 256, 0, stream>>>(dst, deg);
    scan_kernel<<<1, 1024, 0, stream>>>(deg, rp, cursor);
    fill_kernel<<<EB, 256, 0, stream>>>(src, dst, cursor, es, eidx);

    // ===== layer 1 (heads=4, ch=32) =====
    proj_kernel<true><<<PG, 256, 0, stream>>>(x, w1q, b1q, Qb, NN);
    proj_kernel<true><<<PG, 256, 0, stream>>>(x, w1k, b1k, Kb, NN);
    proj_kernel<true><<<PG, 256, 0, stream>>>(x, w1v, b1v, Vb, NN);
    proj_kernel<false><<<PG, 256, 0, stream>>>(x, w1s, b1s, out, NN);  // skip
    logits_kernel<4, 32><<<EB, 256, 0, stream>>>(Qb, Kb, src, dst, LG,
                                                 0.17677669529663687f);
    gather_kernel<4, true><<<NN, 128, 0, stream>>>(LG, Vb, rp, es, eidx, out);

    // ===== layer 2 (heads=1, ch=128); h lives in `out` =====
    proj_kernel<true><<<PG, 256, 0, stream>>>(out, w2q, b2q, Qb, NN);
    proj_kernel<true><<<PG, 256, 0, stream>>>(out, w2k, b2k, Kb, NN);
    proj_kernel<true><<<PG, 256, 0, stream>>>(out, w2v, b2v, Vb, NN);
    logits_kernel<1, 128><<<EB, 256, 0, stream>>>(Qb, Kb, src, dst, LG,
                                                  0.08838834764831845f);
    proj_inplace_kernel<<<512, 256, 0, stream>>>(out, w2s, b2s, NN);   // skip
    gather_kernel<1, false><<<NN, 128, 0, stream>>>(LG, Vb, rp, es, eidx, out);
}

// Round 6
// 759.308 us; speedup vs baseline: 1.9971x; 1.2809x over previous
//
#include <hip/hip_runtime.h>
#include <hip/hip_bf16.h>

#define NN 50000
#define EE 800000

// ---------- helpers ----------
__device__ __forceinline__ float bfu_lo(unsigned w) { return __uint_as_float(w << 16); }
__device__ __forceinline__ float bfu_hi(unsigned w) { return __uint_as_float(w & 0xffff0000u); }

// ---------- zero words ----------
__global__ __launch_bounds__(256) void zero_kernel(unsigned* __restrict__ p, int n) {
    int i = blockIdx.x * 256 + threadIdx.x;
    if (i < n) p[i] = 0u;
}

// ---------- CSR build: histogram ----------
__global__ __launch_bounds__(256) void hist_kernel(
    const int* __restrict__ dst, unsigned* __restrict__ deg) {
    int e = blockIdx.x * 256 + threadIdx.x;
    if (e < EE) atomicAdd(&deg[dst[e]], 1u);
}

// ---------- two-level scan ----------
// A: block-local exclusive scan -> rp, block total -> bsum
__global__ __launch_bounds__(256) void scanA_kernel(
    const unsigned* __restrict__ deg, unsigned* __restrict__ rp,
    unsigned* __restrict__ bsum) {
    __shared__ unsigned s[256];
    int tid = threadIdx.x;
    int i = blockIdx.x * 256 + tid;
    unsigned v = (i < NN) ? deg[i] : 0u;
    s[tid] = v;
    __syncthreads();
#pragma unroll
    for (int o = 1; o < 256; o <<= 1) {
        unsigned t2 = (tid >= o) ? s[tid - o] : 0u;
        __syncthreads();
        s[tid] += t2;
        __syncthreads();
    }
    if (i < NN) rp[i] = s[tid] - v;           // local exclusive
    if (tid == 255) bsum[blockIdx.x] = s[255];
}
// B: exclusive scan of 196 block sums (1 block)
__global__ __launch_bounds__(256) void scanB_kernel(
    unsigned* __restrict__ bsum, int nb) {
    __shared__ unsigned s[256];
    int tid = threadIdx.x;
    unsigned v = (tid < nb) ? bsum[tid] : 0u;
    s[tid] = v;
    __syncthreads();
#pragma unroll
    for (int o = 1; o < 256; o <<= 1) {
        unsigned t2 = (tid >= o) ? s[tid - o] : 0u;
        __syncthreads();
        s[tid] += t2;
        __syncthreads();
    }
    if (tid < nb) bsum[tid] = s[tid] - v;     // exclusive, in place
}
// C: add block offset; init cursor; finalize rp[NN]
__global__ __launch_bounds__(256) void scanC_kernel(
    unsigned* __restrict__ rp, const unsigned* __restrict__ bsum,
    unsigned* __restrict__ cursor) {
    int i = blockIdx.x * 256 + threadIdx.x;
    if (i < NN) {
        unsigned v = rp[i] + bsum[blockIdx.x];
        rp[i] = v;
        cursor[i] = v;
    }
    if (i == 0) rp[NN] = EE;
}

// ---------- CSR build: fill (src only) ----------
__global__ __launch_bounds__(256) void fill_kernel(
    const int* __restrict__ src, const int* __restrict__ dst,
    unsigned* __restrict__ cursor, int* __restrict__ es) {
    int e = blockIdx.x * 256 + threadIdx.x;
    if (e >= EE) return;
    unsigned pos = atomicAdd(&cursor[dst[e]], 1u);
    es[pos] = src[e];
}

// ---------- GEMM: out[n,128] = x[n,128] @ w[128,128] + b ----------
template <bool OUT_BF16>
__global__ __launch_bounds__(256) void proj_kernel(
    const float* __restrict__ x, const float* __restrict__ w,
    const float* __restrict__ b, void* __restrict__ outv, int n) {
    __shared__ float wl[128 * 64];
    __shared__ float xl[16 * 128];
    __shared__ float bl[64];
    int tid = threadIdx.x;
    int col0 = blockIdx.y * 64;
    for (int i = tid; i < 128 * 64; i += 256)
        wl[i] = w[(i >> 6) * 128 + col0 + (i & 63)];
    if (tid < 64) bl[tid] = b[col0 + tid];
    __syncthreads();

    int sub = tid >> 6;
    int col = tid & 63;
    int ngrp = n >> 4;
    for (int g = blockIdx.x; g < ngrp; g += gridDim.x) {
        int r0 = g << 4;
        __syncthreads();
        const float4* xs = (const float4*)(x + (size_t)r0 * 128);
        ((float4*)xl)[tid] = xs[tid];
        ((float4*)xl)[tid + 256] = xs[tid + 256];
        __syncthreads();
        float a0 = bl[col], a1 = a0, a2 = a0, a3 = a0;
#pragma unroll
        for (int k = 0; k < 128; ++k) {
            float wv = wl[k * 64 + col];
            a0 = fmaf(xl[(sub + 0) * 128 + k], wv, a0);
            a1 = fmaf(xl[(sub + 4) * 128 + k], wv, a1);
            a2 = fmaf(xl[(sub + 8) * 128 + k], wv, a2);
            a3 = fmaf(xl[(sub + 12) * 128 + k], wv, a3);
        }
        size_t base = (size_t)r0 * 128 + col0 + col;
        if (OUT_BF16) {
            __hip_bfloat16* o = (__hip_bfloat16*)outv;
            o[base + (size_t)(sub + 0) * 128] = __float2bfloat16(a0);
            o[base + (size_t)(sub + 4) * 128] = __float2bfloat16(a1);
            o[base + (size_t)(sub + 8) * 128] = __float2bfloat16(a2);
            o[base + (size_t)(sub + 12) * 128] = __float2bfloat16(a3);
        } else {
            float* o = (float*)outv;
            o[base + (size_t)(sub + 0) * 128] = a0;
            o[base + (size_t)(sub + 4) * 128] = a1;
            o[base + (size_t)(sub + 8) * 128] = a2;
            o[base + (size_t)(sub + 12) * 128] = a3;
        }
    }
}

// ---------- in-place GEMM: xo = xo @ w + b ----------
__global__ __launch_bounds__(256) void proj_inplace_kernel(
    float* __restrict__ xo, const float* __restrict__ w,
    const float* __restrict__ b, int n) {
    __shared__ float wl[128 * 64];
    __shared__ float xl[16 * 128];
    __shared__ float bl[128];
    int tid = threadIdx.x;
    if (tid < 128) bl[tid] = b[tid];
    int sub = tid >> 6;
    int col = tid & 63;
    int ngrp = n >> 4;
    for (int g = blockIdx.x; g < ngrp; g += gridDim.x) {
        int r0 = g << 4;
        __syncthreads();
        const float4* xs = (const float4*)(xo + (size_t)r0 * 128);
        ((float4*)xl)[tid] = xs[tid];
        ((float4*)xl)[tid + 256] = xs[tid + 256];
#pragma unroll 1
        for (int half = 0; half < 2; ++half) {
            int col0 = half * 64;
            for (int i = tid; i < 128 * 64; i += 256)
                wl[i] = w[(i >> 6) * 128 + col0 + (i & 63)];
            __syncthreads();
            float a0 = bl[col0 + col], a1 = a0, a2 = a0, a3 = a0;
#pragma unroll
            for (int k = 0; k < 128; ++k) {
                float wv = wl[k * 64 + col];
                a0 = fmaf(xl[(sub + 0) * 128 + k], wv, a0);
                a1 = fmaf(xl[(sub + 4) * 128 + k], wv, a1);
                a2 = fmaf(xl[(sub + 8) * 128 + k], wv, a2);
                a3 = fmaf(xl[(sub + 12) * 128 + k], wv, a3);
            }
            size_t base = (size_t)r0 * 128 + col0 + col;
            xo[base + (size_t)(sub + 0) * 128] = a0;
            xo[base + (size_t)(sub + 4) * 128] = a1;
            xo[base + (size_t)(sub + 8) * 128] = a2;
            xo[base + (size_t)(sub + 12) * 128] = a3;
            __syncthreads();
        }
    }
}

// ---------- fused attention gather: logits + online softmax + PV ----------
// One 128-thread block per dst node. Chunk = 16 edges; 8 threads/edge for
// the QK dot; thread t owns output channel t in the PV phase.
template <int H, bool RELU>
__global__ __launch_bounds__(128) void gather_kernel(
    const __hip_bfloat16* __restrict__ Q, const __hip_bfloat16* __restrict__ K,
    const __hip_bfloat16* __restrict__ V,
    const unsigned* __restrict__ rp, const int* __restrict__ es,
    float* __restrict__ O, float scale) {
    __shared__ float Pl[16 * H];
    __shared__ int esl[16];
    int d = blockIdx.x;
    int tid = threadIdx.x;
    int beg = (int)rp[d], end = (int)rp[d + 1];
    const int e_slot = tid >> 3;   // 0..15
    const int c_grp = tid & 7;     // 0..7 (16 channels each)
    const int h = (H == 4) ? (tid >> 5) : 0;   // PV-phase head

    // Q fragment for dot phase: channels c_grp*16 .. +16 (2 x uint4 bf16)
    const uint4* qp = (const uint4*)(Q + (size_t)d * 128);
    uint4 q0 = qp[c_grp * 2 + 0];
    uint4 q1 = qp[c_grp * 2 + 1];

    float m = -3.4e38f, ssum = 0.f, acc = 0.f;
    for (int cs = beg; cs < end; cs += 16) {
        int len = min(16, end - cs);
        __syncthreads();   // Pl/esl reusable
        if (tid < len) esl[tid] = es[cs + tid];
        __syncthreads();
        if (e_slot < len) {
            int s = esl[e_slot];
            const uint4* kp = (const uint4*)(K + (size_t)s * 128);
            uint4 k0 = kp[c_grp * 2 + 0];
            uint4 k1 = kp[c_grp * 2 + 1];
            float p = 0.f;
            p += bfu_lo(k0.x) * bfu_lo(q0.x) + bfu_hi(k0.x) * bfu_hi(q0.x);
            p += bfu_lo(k0.y) * bfu_lo(q0.y) + bfu_hi(k0.y) * bfu_hi(q0.y);
            p += bfu_lo(k0.z) * bfu_lo(q0.z) + bfu_hi(k0.z) * bfu_hi(q0.z);
            p += bfu_lo(k0.w) * bfu_lo(q0.w) + bfu_hi(k0.w) * bfu_hi(q0.w);
            p += bfu_lo(k1.x) * bfu_lo(q1.x) + bfu_hi(k1.x) * bfu_hi(q1.x);
            p += bfu_lo(k1.y) * bfu_lo(q1.y) + bfu_hi(k1.y) * bfu_hi(q1.y);
            p += bfu_lo(k1.z) * bfu_lo(q1.z) + bfu_hi(k1.z) * bfu_hi(q1.z);
            p += bfu_lo(k1.w) * bfu_lo(q1.w) + bfu_hi(k1.w) * bfu_hi(q1.w);
            if (H == 4) {
                p += __shfl_xor(p, 1);             // pair within head
                if ((c_grp & 1) == 0)
                    Pl[e_slot * 4 + (c_grp >> 1)] = p * scale;
            } else {
                p += __shfl_xor(p, 1);
                p += __shfl_xor(p, 2);
                p += __shfl_xor(p, 4);
                if (c_grp == 0) Pl[e_slot] = p * scale;
            }
        }
        __syncthreads();
        // chunk max for own head (broadcast LDS reads, redundant per thread)
        float cm = -3.4e38f;
        for (int j = 0; j < len; ++j) cm = fmaxf(cm, Pl[j * H + h]);
        float nm = fmaxf(m, cm);
        float sc = __expf(m - nm);    // 0 on first chunk
        acc *= sc;
        ssum *= sc;
        m = nm;
        // PV accumulate; recompute exp on the fly
        for (int j = 0; j < len; ++j) {
            float w = __expf(Pl[j * H + h] - nm);
            ssum += w;
            unsigned short vb =
                ((const unsigned short*)V)[(size_t)esl[j] * 128 + tid];
            acc = fmaf(w, __uint_as_float((unsigned)vb << 16), acc);
        }
    }
    size_t oi = (size_t)d * 128 + tid;
    float val = O[oi] + acc / (ssum + 1e-16f);
    if (RELU) val = fmaxf(val, 0.f);
    O[oi] = val;
}

extern "C" void kernel_launch(void* const* d_in, const int* in_sizes, int n_in,
                              void* d_out, int out_size, void* d_ws, size_t ws_size,
                              hipStream_t stream) {
    const float* x  = (const float*)d_in[0];
    const int* ei   = (const int*)d_in[1];
    const int* src  = ei;
    const int* dst  = ei + EE;
    const float* w1q = (const float*)d_in[2];  const float* b1q = (const float*)d_in[3];
    const float* w1k = (const float*)d_in[4];  const float* b1k = (const float*)d_in[5];
    const float* w1v = (const float*)d_in[6];  const float* b1v = (const float*)d_in[7];
    const float* w1s = (const float*)d_in[8];  const float* b1s = (const float*)d_in[9];
    const float* w2q = (const float*)d_in[10]; const float* b2q = (const float*)d_in[11];
    const float* w2k = (const float*)d_in[12]; const float* b2k = (const float*)d_in[13];
    const float* w2v = (const float*)d_in[14]; const float* b2v = (const float*)d_in[15];
    const float* w2s = (const float*)d_in[16]; const float* b2s = (const float*)d_in[17];
    float* out = (float*)d_out;   // layer-1 accumulator, h, final output

    const size_t NF = (size_t)NN * 128;
    // ws layout (~42.3 MB): bf16 QKV first (16B aligned), then CSR ints
    __hip_bfloat16* Qb = (__hip_bfloat16*)d_ws;       // N*128 bf16
    __hip_bfloat16* Kb = Qb + NF;
    __hip_bfloat16* Vb = Kb + NF;
    unsigned* deg = (unsigned*)(Vb + NF);             // N
    unsigned* cursor = deg + NN;                      // N
    unsigned* rp = cursor + NN;                       // N+1
    unsigned* bsum = rp + NN + 1;                     // 256
    int* es = (int*)(bsum + 256);                     // E

    const dim3 PG(512, 2);
    const int EB = (EE + 255) / 256;
    const int NB = (NN + 255) / 256;   // 196

    // ===== CSR build (shared by both layers) =====
    zero_kernel<<<NB, 256, 0, stream>>>(deg, NN);
    hist_kernel<<<EB, 256, 0, stream>>>(dst, deg);
    scanA_kernel<<<NB, 256, 0, stream>>>(deg, rp, bsum);
    scanB_kernel<<<1, 256, 0, stream>>>(bsum, NB);
    scanC_kernel<<<NB, 256, 0, stream>>>(rp, bsum, cursor);
    fill_kernel<<<EB, 256, 0, stream>>>(src, dst, cursor, es);

    // ===== layer 1 (heads=4, ch=32) =====
    proj_kernel<true><<<PG, 256, 0, stream>>>(x, w1q, b1q, Qb, NN);
    proj_kernel<true><<<PG, 256, 0, stream>>>(x, w1k, b1k, Kb, NN);
    proj_kernel<true><<<PG, 256, 0, stream>>>(x, w1v, b1v, Vb, NN);
    proj_kernel<false><<<PG, 256, 0, stream>>>(x, w1s, b1s, out, NN);  // skip
    gather_kernel<4, true><<<NN, 128, 0, stream>>>(Qb, Kb, Vb, rp, es, out,
                                                   0.17677669529663687f);

    // ===== layer 2 (heads=1, ch=128); h lives in `out` =====
    proj_kernel<true><<<PG, 256, 0, stream>>>(out, w2q, b2q, Qb, NN);
    proj_kernel<true><<<PG, 256, 0, stream>>>(out, w2k, b2k, Kb, NN);
    proj_kernel<true><<<PG, 256, 0, stream>>>(out, w2v, b2v, Vb, NN);
    proj_inplace_kernel<<<512, 256, 0, stream>>>(out, w2s, b2s, NN);   // skip
    gather_kernel<1, false><<<NN, 128, 0, stream>>>(Qb, Kb, Vb, rp, es, out,
                                                    0.08838834764831845f);
}

// Round 9
// 512.074 us; speedup vs baseline: 2.9614x; 1.4828x over previous
//
#include <hip/hip_runtime.h>

#define NN 50000
#define EE 800000
#define NTILES 3125   // 50000/16
#define NQUADS 782    // ceil(3125/4)

using short8 = __attribute__((ext_vector_type(8))) short;
using f32x4  = __attribute__((ext_vector_type(4))) float;

// ---------- helpers ----------
__device__ __forceinline__ unsigned short f2bf(float f) {   // RNE f32->bf16
    unsigned u = __float_as_uint(f);
    unsigned r = u + 0x7fffu + ((u >> 16) & 1u);
    return (unsigned short)(r >> 16);
}
__device__ __forceinline__ float bf2f(unsigned short h) {
    return __uint_as_float((unsigned)h << 16);
}
__device__ __forceinline__ float bfu_lo(unsigned w) { return __uint_as_float(w << 16); }
__device__ __forceinline__ float bfu_hi(unsigned w) { return __uint_as_float(w & 0xffff0000u); }

// ---------- zero words ----------
__global__ __launch_bounds__(256) void zero_kernel(unsigned* __restrict__ p, int n) {
    int i = blockIdx.x * 256 + threadIdx.x;
    if (i < n) p[i] = 0u;
}

// ---------- pack W (f32 128x128) -> hi/lo bf16 B-fragments ----------
__global__ __launch_bounds__(256) void prepw_kernel(
    const float* __restrict__ w, uint4* __restrict__ wf) {
    int idx = blockIdx.x * 256 + threadIdx.x;
    if (idx >= 2048) return;
    int c = idx & 127;
    int g = (idx >> 7) & 3;
    int kb = idx >> 9;
    int k0 = kb * 32 + g * 8;
    unsigned th[8], tl[8];
#pragma unroll
    for (int j = 0; j < 8; ++j) {
        float v = w[(size_t)(k0 + j) * 128 + c];
        unsigned short h = f2bf(v);
        th[j] = h;
        tl[j] = f2bf(v - bf2f(h));
    }
    uint4 uh, ul;
    uh.x = th[0] | (th[1] << 16); uh.y = th[2] | (th[3] << 16);
    uh.z = th[4] | (th[5] << 16); uh.w = th[6] | (th[7] << 16);
    ul.x = tl[0] | (tl[1] << 16); ul.y = tl[2] | (tl[3] << 16);
    ul.z = tl[4] | (tl[5] << 16); ul.w = tl[6] | (tl[7] << 16);
    wf[idx] = uh;
    wf[2048 + idx] = ul;
}

// ---------- CSR build ----------
__global__ __launch_bounds__(256) void hist_kernel(
    const int* __restrict__ dst, unsigned* __restrict__ deg) {
    int e = blockIdx.x * 256 + threadIdx.x;
    if (e < EE) atomicAdd(&deg[dst[e]], 1u);
}
__global__ __launch_bounds__(256) void scanA_kernel(
    const unsigned* __restrict__ deg, unsigned* __restrict__ rp,
    unsigned* __restrict__ bsum) {
    __shared__ unsigned s[256];
    int tid = threadIdx.x;
    int i = blockIdx.x * 256 + tid;
    unsigned v = (i < NN) ? deg[i] : 0u;
    s[tid] = v;
    __syncthreads();
#pragma unroll
    for (int o = 1; o < 256; o <<= 1) {
        unsigned t2 = (tid >= o) ? s[tid - o] : 0u;
        __syncthreads();
        s[tid] += t2;
        __syncthreads();
    }
    if (i < NN) rp[i] = s[tid] - v;
    if (tid == 255) bsum[blockIdx.x] = s[255];
}
__global__ __launch_bounds__(256) void scanB_kernel(
    unsigned* __restrict__ bsum, int nb) {
    __shared__ unsigned s[256];
    int tid = threadIdx.x;
    unsigned v = (tid < nb) ? bsum[tid] : 0u;
    s[tid] = v;
    __syncthreads();
#pragma unroll
    for (int o = 1; o < 256; o <<= 1) {
        unsigned t2 = (tid >= o) ? s[tid - o] : 0u;
        __syncthreads();
        s[tid] += t2;
        __syncthreads();
    }
    if (tid < nb) bsum[tid] = s[tid] - v;
}
__global__ __launch_bounds__(256) void scanC_kernel(
    unsigned* __restrict__ rp, const unsigned* __restrict__ bsum,
    unsigned* __restrict__ cursor) {
    int i = blockIdx.x * 256 + threadIdx.x;
    if (i < NN) {
        unsigned v = rp[i] + bsum[blockIdx.x];
        rp[i] = v;
        cursor[i] = v;
    }
    if (i == 0) rp[NN] = EE;
}
__global__ __launch_bounds__(256) void fill_kernel(
    const int* __restrict__ src, const int* __restrict__ dst,
    unsigned* __restrict__ cursor, unsigned short* __restrict__ es) {
    int e = blockIdx.x * 256 + threadIdx.x;
    if (e >= EE) return;
    unsigned pos = atomicAdd(&cursor[dst[e]], 1u);
    es[pos] = (unsigned short)src[e];
}

// ---------- MFMA GEMM (fp32-accurate via bf16 hi/lo split) ----------
// out[50000,128] = act(f32) @ W + b. One block = 4 waves = 4 row-tiles of 16.
// In-place safe (act may == outv): each wave registers its A rows before any
// store; a tile's rows are touched only by its owning wave. Grid == NQUADS.
template <bool OUT_BF16>
__global__ __launch_bounds__(256) void mfma_proj(
    const float* act, const uint4* __restrict__ Wf,
    const float* __restrict__ bias, void* outv) {
    __shared__ uint4 wls[4096];     // 64 KB: hi [0,2048) | lo [2048,4096)
    int tid = threadIdx.x;
    for (int i = tid; i < 4096; i += 256) wls[i] = Wf[i];
    __syncthreads();

    int w = tid >> 6;
    int l = tid & 63;
    int lr = l & 15;            // A-row / D-col lane index
    int lg = l >> 4;            // k-group 0..3
    int tile = blockIdx.x * 4 + w;
    if (tile >= NTILES) return;

    const float4* rp4 = (const float4*)(act + (size_t)(tile * 16 + lr) * 128);
    short8 ah[4], al[4];
#pragma unroll
    for (int kb = 0; kb < 4; ++kb) {
        float4 v0 = rp4[kb * 8 + lg * 2];
        float4 v1 = rp4[kb * 8 + lg * 2 + 1];
        float xs[8] = {v0.x, v0.y, v0.z, v0.w, v1.x, v1.y, v1.z, v1.w};
#pragma unroll
        for (int j = 0; j < 8; ++j) {
            unsigned short hi = f2bf(xs[j]);
            ah[kb][j] = (short)hi;
            al[kb][j] = (short)f2bf(xs[j] - bf2f(hi));
        }
    }
#pragma unroll
    for (int half = 0; half < 2; ++half) {
#pragma unroll
        for (int ct = 0; ct < 4; ++ct) {
            int coff = half * 64 + ct * 16 + lr;
            f32x4 acc = {0.f, 0.f, 0.f, 0.f};
#pragma unroll
            for (int kb = 0; kb < 4; ++kb) {
                short8 bh = *reinterpret_cast<const short8*>(
                    &wls[(kb * 4 + lg) * 128 + coff]);
                short8 blo = *reinterpret_cast<const short8*>(
                    &wls[2048 + (kb * 4 + lg) * 128 + coff]);
                acc = __builtin_amdgcn_mfma_f32_16x16x32_bf16(ah[kb], bh, acc, 0, 0, 0);
                acc = __builtin_amdgcn_mfma_f32_16x16x32_bf16(al[kb], bh, acc, 0, 0, 0);
                acc = __builtin_amdgcn_mfma_f32_16x16x32_bf16(ah[kb], blo, acc, 0, 0, 0);
            }
            float bv = bias[coff];
#pragma unroll
            for (int r = 0; r < 4; ++r) {
                int orow = tile * 16 + lg * 4 + r;
                float v = acc[r] + bv;
                if (OUT_BF16)
                    ((unsigned short*)outv)[(size_t)orow * 128 + coff] = f2bf(v);
                else
                    ((float*)outv)[(size_t)orow * 128 + coff] = v;
            }
        }
    }
}

// ---------- fused attention gather: logits + online softmax + PV ----------
template <int H, bool RELU>
__global__ __launch_bounds__(128) void gather_kernel(
    const unsigned short* __restrict__ Q, const unsigned short* __restrict__ K,
    const unsigned short* __restrict__ V,
    const unsigned* __restrict__ rp, const unsigned short* __restrict__ es,
    float* __restrict__ O, float scale) {
    __shared__ float Pl[16 * H];
    __shared__ int esl[16];
    int d = blockIdx.x;
    int tid = threadIdx.x;
    int beg = (int)rp[d], end = (int)rp[d + 1];
    const int e_slot = tid >> 3;
    const int c_grp = tid & 7;
    const int h = (H == 4) ? (tid >> 5) : 0;

    const uint4* qp = (const uint4*)(Q + (size_t)d * 128);
    uint4 q0 = qp[c_grp * 2 + 0];
    uint4 q1 = qp[c_grp * 2 + 1];

    float m = -3.4e38f, ssum = 0.f, acc = 0.f;
    for (int cs = beg; cs < end; cs += 16) {
        int len = min(16, end - cs);
        __syncthreads();
        if (tid < len) esl[tid] = (int)es[cs + tid];
        __syncthreads();
        if (e_slot < len) {
            int s = esl[e_slot];
            const uint4* kp = (const uint4*)(K + (size_t)s * 128);
            uint4 k0 = kp[c_grp * 2 + 0];
            uint4 k1 = kp[c_grp * 2 + 1];
            float p = 0.f;
            p += bfu_lo(k0.x) * bfu_lo(q0.x) + bfu_hi(k0.x) * bfu_hi(q0.x);
            p += bfu_lo(k0.y) * bfu_lo(q0.y) + bfu_hi(k0.y) * bfu_hi(q0.y);
            p += bfu_lo(k0.z) * bfu_lo(q0.z) + bfu_hi(k0.z) * bfu_hi(q0.z);
            p += bfu_lo(k0.w) * bfu_lo(q0.w) + bfu_hi(k0.w) * bfu_hi(q0.w);
            p += bfu_lo(k1.x) * bfu_lo(q1.x) + bfu_hi(k1.x) * bfu_hi(q1.x);
            p += bfu_lo(k1.y) * bfu_lo(q1.y) + bfu_hi(k1.y) * bfu_hi(q1.y);
            p += bfu_lo(k1.z) * bfu_lo(q1.z) + bfu_hi(k1.z) * bfu_hi(q1.z);
            p += bfu_lo(k1.w) * bfu_lo(q1.w) + bfu_hi(k1.w) * bfu_hi(q1.w);
            if (H == 4) {
                p += __shfl_xor(p, 1);
                if ((c_grp & 1) == 0)
                    Pl[e_slot * 4 + (c_grp >> 1)] = p * scale;
            } else {
                p += __shfl_xor(p, 1);
                p += __shfl_xor(p, 2);
                p += __shfl_xor(p, 4);
                if (c_grp == 0) Pl[e_slot] = p * scale;
            }
        }
        __syncthreads();
        float cm = -3.4e38f;
        for (int j = 0; j < len; ++j) cm = fmaxf(cm, Pl[j * H + h]);
        float nm = fmaxf(m, cm);
        float sc = __expf(m - nm);
        __syncthreads();   // RACE FIX: all cm reads done BEFORE exp overwrite
        int jj = (H == 4) ? (tid & 31) : tid;
        if (jj < len) Pl[jj * H + h] = __expf(Pl[jj * H + h] - nm);
        __syncthreads();
        acc *= sc;
        ssum *= sc;
        m = nm;
        for (int j = 0; j < len; ++j) {
            float wv = Pl[j * H + h];
            ssum += wv;
            unsigned short vb = V[(size_t)esl[j] * 128 + tid];
            acc = fmaf(wv, bf2f(vb), acc);
        }
    }
    size_t oi = (size_t)d * 128 + tid;
    float val = O[oi] + acc / (ssum + 1e-16f);
    if (RELU) val = fmaxf(val, 0.f);
    O[oi] = val;
}

extern "C" void kernel_launch(void* const* d_in, const int* in_sizes, int n_in,
                              void* d_out, int out_size, void* d_ws, size_t ws_size,
                              hipStream_t stream) {
    const float* x  = (const float*)d_in[0];
    const int* ei   = (const int*)d_in[1];
    const int* src  = ei;
    const int* dst  = ei + EE;
    const float* w1q = (const float*)d_in[2];  const float* b1q = (const float*)d_in[3];
    const float* w1k = (const float*)d_in[4];  const float* b1k = (const float*)d_in[5];
    const float* w1v = (const float*)d_in[6];  const float* b1v = (const float*)d_in[7];
    const float* w1s = (const float*)d_in[8];  const float* b1s = (const float*)d_in[9];
    const float* w2q = (const float*)d_in[10]; const float* b2q = (const float*)d_in[11];
    const float* w2k = (const float*)d_in[12]; const float* b2k = (const float*)d_in[13];
    const float* w2v = (const float*)d_in[14]; const float* b2v = (const float*)d_in[15];
    const float* w2s = (const float*)d_in[16]; const float* b2s = (const float*)d_in[17];
    float* out = (float*)d_out;   // skip accumulator, f32 h, final output

    const size_t NF = (size_t)NN * 128;
    // ws layout (~41.2 MB): Qb | Kb | Vb (bf16) | Wf[8x4096 uint4] | CSR
    unsigned short* Qb = (unsigned short*)d_ws;
    unsigned short* Kb = Qb + NF;
    unsigned short* Vb = Kb + NF;
    uint4* Wf = (uint4*)(Vb + NF);                 // 8 * 4096 uint4 (hi+lo)
    unsigned* deg = (unsigned*)(Wf + 8 * 4096);    // N
    unsigned* cursor = deg + NN;                   // N
    unsigned* rp = cursor + NN;                    // N+1
    unsigned* bsum = rp + NN + 1;                  // 256
    unsigned short* es = (unsigned short*)(bsum + 256);   // E (ushort)

    const int EB = (EE + 255) / 256;
    const int NB = (NN + 255) / 256;

    // ===== prep: pack weights (hi/lo), CSR =====
    prepw_kernel<<<8, 256, 0, stream>>>(w1q, Wf + 0 * 4096);
    prepw_kernel<<<8, 256, 0, stream>>>(w1k, Wf + 1 * 4096);
    prepw_kernel<<<8, 256, 0, stream>>>(w1v, Wf + 2 * 4096);
    prepw_kernel<<<8, 256, 0, stream>>>(w1s, Wf + 3 * 4096);
    prepw_kernel<<<8, 256, 0, stream>>>(w2q, Wf + 4 * 4096);
    prepw_kernel<<<8, 256, 0, stream>>>(w2k, Wf + 5 * 4096);
    prepw_kernel<<<8, 256, 0, stream>>>(w2v, Wf + 6 * 4096);
    prepw_kernel<<<8, 256, 0, stream>>>(w2s, Wf + 7 * 4096);
    zero_kernel<<<NB, 256, 0, stream>>>(deg, NN);
    hist_kernel<<<EB, 256, 0, stream>>>(dst, deg);
    scanA_kernel<<<NB, 256, 0, stream>>>(deg, rp, bsum);
    scanB_kernel<<<1, 256, 0, stream>>>(bsum, NB);
    scanC_kernel<<<NB, 256, 0, stream>>>(rp, bsum, cursor);
    fill_kernel<<<EB, 256, 0, stream>>>(src, dst, cursor, es);

    // ===== layer 1 (heads=4, ch=32) =====
    mfma_proj<true><<<NQUADS, 256, 0, stream>>>(x, Wf + 0 * 4096, b1q, Qb);
    mfma_proj<true><<<NQUADS, 256, 0, stream>>>(x, Wf + 1 * 4096, b1k, Kb);
    mfma_proj<true><<<NQUADS, 256, 0, stream>>>(x, Wf + 2 * 4096, b1v, Vb);
    mfma_proj<false><<<NQUADS, 256, 0, stream>>>(x, Wf + 3 * 4096, b1s, out);
    gather_kernel<4, true><<<NN, 128, 0, stream>>>(Qb, Kb, Vb, rp, es, out,
                                                   0.17677669529663687f);

    // ===== layer 2 (heads=1, ch=128); h = f32 in `out` =====
    mfma_proj<true><<<NQUADS, 256, 0, stream>>>(out, Wf + 4 * 4096, b2q, Qb);
    mfma_proj<true><<<NQUADS, 256, 0, stream>>>(out, Wf + 5 * 4096, b2k, Kb);
    mfma_proj<true><<<NQUADS, 256, 0, stream>>>(out, Wf + 6 * 4096, b2v, Vb);
    // skip2 in place: out = out @ w2s + b2s
    mfma_proj<false><<<NQUADS, 256, 0, stream>>>(out, Wf + 7 * 4096, b2s, out);
    gather_kernel<1, false><<<NN, 128, 0, stream>>>(Qb, Kb, Vb, rp, es, out,
                                                    0.08838834764831845f);
}